// Round 1
// baseline (75.775 us; speedup 1.0000x reference)
//
#include <hip/hip_runtime.h>
#include <stdint.h>

// SampleChamfer: out = sum_i min_k ||pa_i - pb_k||^2
// pa_i = a[:, a_idx[i]], pb_k = b[:, b_idx[k]], fp32 scalar out.
//
// R5: kill the 1M contended device-scope atomicMin (theory: ~55 us of the
// 69.7) by making the min block-local. 2 dispatches:
//  P: gather ONCE -> pa4[i]=(ax,ay,az,||a||^2), pb4[i]=(-2bx,-2by,-2bz,||b||^2);
//     zeroes d_out. (unchanged from R4 except: no minarr init)
//  M: grid 512 blocks x 256 threads; each block owns 16 a-points and streams
//     ALL 8192 b-points through double-buffered LDS (8 chunks of 1024 float4,
//     padded u+(u>>4) -> 2-way bank aliasing = free). Thread (g=t&3, s=t>>2):
//     4 a-points in registers x 16 b-points/chunk => 16 VALU ops per
//     ds_read_b128 (VALU-bound). One barrier per chunk; global prefetch of
//     chunk c+1 issued before compute of chunk c (latency hidden).
//     Block-local min: shfl_xor(4,8,16,32) + [4][16] LDS cross-wave combine,
//     + ||a||^2, 16-lane sum, ONE atomicAdd per block. No minarr, no R pass.

#define MT    256                 // min-kernel threads
#define APB   16                  // a-points per block -> grid 512
#define NPA   4                   // a-points per thread-group
#define CH    1024                // b-points per LDS chunk
#define NCH   8                   // 8192 / CH
#define CPAD  (CH + CH / 16)      // 1088 float4 (pad every 16)

__global__ __launch_bounds__(128)
void chamfer_pack_kernel(const float* __restrict__ a,
                         const float* __restrict__ b,
                         const int* __restrict__ a_idx,
                         const int* __restrict__ b_idx,
                         float4* __restrict__ pa4,
                         float4* __restrict__ pb4,
                         float* __restrict__ out,
                         int N, int n) {
    int i = blockIdx.x * 128 + threadIdx.x;   // 64 blocks x 128 threads
    if (i < n) {
        int ai = a_idx[i];
        float x = a[ai], y = a[N + ai], z = a[2 * N + ai];
        pa4[i] = make_float4(x, y, z, x * x + y * y + z * z);
        int bi = b_idx[i];
        float u = b[bi], v = b[N + bi], w = b[2 * N + bi];
        pb4[i] = make_float4(-2.f * u, -2.f * v, -2.f * w,
                             u * u + v * v + w * w);
    }
    if (i == 0) out[0] = 0.f;               // d_out is poisoned each iter
}

__global__ __launch_bounds__(MT)
void chamfer_min_kernel(const float4* __restrict__ pa4,
                        const float4* __restrict__ pb4,
                        float* __restrict__ out) {
    __shared__ float4 tile[2][CPAD];        // double-buffered b chunks
    __shared__ float  red[4][APB];          // cross-wave min combine

    const int t = threadIdx.x;
    const int g = t & 3;                    // a-group (4 a-points each)
    const int s = t >> 2;                   // b-slice 0..63 (16 b/chunk)
    const int abase = blockIdx.x * APB;

    float ax[NPA], ay[NPA], az[NPA], mn[NPA];
#pragma unroll
    for (int m = 0; m < NPA; ++m) {
        float4 p = pa4[abase + g * NPA + m];   // 16 distinct lines, broadcast
        ax[m] = p.x; ay[m] = p.y; az[m] = p.z;
        mn[m] = 3.4e38f;
    }

    // prologue: chunk 0 into registers
    float4 r0 = pb4[t], r1 = pb4[t + 256], r2 = pb4[t + 512], r3 = pb4[t + 768];

    for (int c = 0; c < NCH; ++c) {
        float4* tl = tile[c & 1];
        {   // padded stores: u + (u>>4), ~2-way write aliasing (free)
            int u;
            u = t;        tl[u + (u >> 4)] = r0;
            u = t + 256;  tl[u + (u >> 4)] = r1;
            u = t + 512;  tl[u + (u >> 4)] = r2;
            u = t + 768;  tl[u + (u >> 4)] = r3;
        }
        __syncthreads();                    // one barrier per chunk (see note)
        if (c + 1 < NCH) {                  // prefetch chunk c+1; consumed at
            const float4* src = pb4 + (c + 1) * CH;   // next iter's ds_writes
            r0 = src[t]; r1 = src[t + 256]; r2 = src[t + 512]; r3 = src[t + 768];
        }
        // slice s reads b-points [s*16, s*16+16): padded addr = s*17 + j.
        // per wave: 16 distinct addrs, (s+j)&7 covers each bank-quad 2x ->
        // 2-way conflict = free (m136); each addr broadcast to 4 lanes.
        const float4* row = &tl[s * 17];
#pragma unroll
        for (int j = 0; j < 16; ++j) {
            float4 bt = row[j];
#pragma unroll
            for (int m = 0; m < NPA; ++m) {
                float d = fmaf(bt.x, ax[m],
                          fmaf(bt.y, ay[m],
                          fmaf(bt.z, az[m], bt.w)));
                mn[m] = fminf(mn[m], d);
            }
        }
        // no trailing barrier: iter c+1 writes the OTHER buffer; reuse of this
        // buffer (iter c+2) is fenced by iter c+1's __syncthreads().
    }

    // min across the 16 same-g lanes of each wave (lanes l, l^4, ... share g)
#pragma unroll
    for (int m = 0; m < NPA; ++m) {
        float v = mn[m];
        v = fminf(v, __shfl_xor(v, 4, 64));
        v = fminf(v, __shfl_xor(v, 8, 64));
        v = fminf(v, __shfl_xor(v, 16, 64));
        v = fminf(v, __shfl_xor(v, 32, 64));
        mn[m] = v;
    }
    if ((t & 63) < 4) {                     // lane==g holds the wave min
#pragma unroll
        for (int m = 0; m < NPA; ++m)
            red[t >> 6][(t & 3) * NPA + m] = mn[m];
    }
    __syncthreads();
    if (t < APB) {                          // t == a_local
        float v = fminf(fminf(red[0][t], red[1][t]),
                        fminf(red[2][t], red[3][t]));
        v += pa4[abase + t].w;              // + ||a||^2 after the min
        v += __shfl_down(v, 8, 16);
        v += __shfl_down(v, 4, 16);
        v += __shfl_down(v, 2, 16);
        v += __shfl_down(v, 1, 16);
        if (t == 0) atomicAdd(out, v);      // out pre-zeroed by pack kernel
    }
}

extern "C" void kernel_launch(void* const* d_in, const int* in_sizes, int n_in,
                              void* d_out, int out_size, void* d_ws, size_t ws_size,
                              hipStream_t stream) {
    const float* a     = (const float*)d_in[0];
    const float* b     = (const float*)d_in[1];
    const int*   a_idx = (const int*)d_in[2];
    const int*   b_idx = (const int*)d_in[3];
    float*       out   = (float*)d_out;

    const int N = in_sizes[0] / 3;   // 16384
    const int n = in_sizes[2];       // 8192

    // ws layout: pa4 [n], pb4 [n]
    float4* pa4 = (float4*)d_ws;
    float4* pb4 = pa4 + n;

    chamfer_pack_kernel<<<n / 128, 128, 0, stream>>>(
        a, b, a_idx, b_idx, pa4, pb4, out, N, n);

    chamfer_min_kernel<<<n / APB, MT, 0, stream>>>(pa4, pb4, out);
}